// Round 1
// baseline (707.977 us; speedup 1.0000x reference)
//
#include <hip/hip_runtime.h>
#include <hip/hip_bf16.h>

#define NN 4096     // layer size n
#define RR 4        // displacement rank
#define BB 8192     // batch
#define CHUNK 64            // t-chunk for prefix kernels
#define NCHUNK (NN / CHUNK) // 64

typedef __bf16 bf16x8 __attribute__((ext_vector_type(8)));
typedef float f32x4 __attribute__((ext_vector_type(4)));
typedef unsigned short u16;
typedef unsigned int u32;

#define GLOBAL_AS(p) ((const __attribute__((address_space(1))) u32*)(p))
#define LDS_AS(p) ((__attribute__((address_space(3))) u32*)(p))

// ---------------------------------------------------------------------------
// Kernel 0: cast x (f32) -> bf16, 8 elements/thread, fully vectorized.
// ---------------------------------------------------------------------------
__device__ inline u32 pack_bf2(float lo, float hi) {
    __hip_bfloat162 h2 = __float22bfloat162_rn(make_float2(lo, hi));
    return *(u32*)&h2;
}

__global__ void cast_x_kernel(const float* __restrict__ x, uint4* __restrict__ xb) {
    size_t i = (size_t)blockIdx.x * 256 + threadIdx.x;  // one 8-elem chunk each
    const float4* x4 = (const float4*)x;
    float4 a = x4[2 * i];
    float4 b = x4[2 * i + 1];
    uint4 o;
    o.x = pack_bf2(a.x, a.y);
    o.y = pack_bf2(a.z, a.w);
    o.z = pack_bf2(b.x, b.y);
    o.w = pack_bf2(b.z, b.w);
    xb[i] = o;
}

// ---------------------------------------------------------------------------
// Kernel 1: block sums S(d,J) = sum_{t in chunk J} q(d,t),
//   q(d,t) = sum_r G[r][(d+t)%n] * H[r][t]
// grid: 16 d-blocks x 64 J = 1024 blocks, 256 threads (one (d,J) each)
// ---------------------------------------------------------------------------
__global__ void ksum_kernel(const float* __restrict__ G, const float* __restrict__ H,
                            float* __restrict__ S) {
    int dblk = blockIdx.x & 15;
    int J = blockIdx.x >> 4;
    int d = dblk * 256 + threadIdx.x;
    int t0 = J * CHUNK;
    float acc = 0.f;
#pragma unroll 4
    for (int tt = 0; tt < CHUNK; ++tt) {
        int t = t0 + tt;
        float h0 = H[t], h1 = H[NN + t], h2 = H[2 * NN + t], h3 = H[3 * NN + t];
        int idx = (d + t) & (NN - 1);
        acc += G[idx] * h0 + G[NN + idx] * h1 + G[2 * NN + idx] * h2 + G[3 * NN + idx] * h3;
    }
    S[d * NCHUNK + J] = acc;
}

// ---------------------------------------------------------------------------
// Kernel 2: prefix within chunk + write W[i][j] (bf16, row-major, j contiguous)
//   W[i,j] = P(d,j) - 0.5*C(d),  i = (d+j) mod n
// Same grid as kernel 1. Stores are diagonal; L2 merges (~65-line window/wave).
// ---------------------------------------------------------------------------
__global__ void kprefix_kernel(const float* __restrict__ G, const float* __restrict__ H,
                               const float* __restrict__ S, u16* __restrict__ W) {
    int dblk = blockIdx.x & 15;
    int J = blockIdx.x >> 4;
    int d = dblk * 256 + threadIdx.x;

    float pre = 0.f, tot = 0.f;
    for (int Jp = 0; Jp < NCHUNK; ++Jp) {
        float v = S[d * NCHUNK + Jp];
        if (Jp < J) pre += v;
        tot += v;
    }
    float acc = pre - 0.5f * tot;

    int t0 = J * CHUNK;
#pragma unroll 4
    for (int tt = 0; tt < CHUNK; ++tt) {
        int t = t0 + tt;
        float h0 = H[t], h1 = H[NN + t], h2 = H[2 * NN + t], h3 = H[3 * NN + t];
        int idx = (d + t) & (NN - 1);  // == output row i
        acc += G[idx] * h0 + G[NN + idx] * h1 + G[2 * NN + idx] * h2 + G[3 * NN + idx] * h3;
        __hip_bfloat16 w = __float2bfloat16(acc);
        W[(size_t)idx * NN + t] = *(u16*)&w;
    }
}

// ---------------------------------------------------------------------------
// Kernel 3: NT GEMM  y[b,i] = sum_j xbf[b,j] * W[i,j]   (f32 accumulate/out)
// m97 structure: 128x128 tile, BK=32, 256 threads (4 waves, 2x2),
// global_load_lds width=16 staging, 16x16x32 bf16 MFMA, 4x4 per wave.
// ---------------------------------------------------------------------------
#define BM 128
#define BN 128
#define BK 32

__global__ __launch_bounds__(256) void gemm_bt_kernel(const u16* __restrict__ A,   // x bf16, M x K
                                                      const u16* __restrict__ Bm,  // W bf16, N x K
                                                      float* __restrict__ C) {
    constexpr int M = BB, N = NN, K = NN;
    (void)M;
    __shared__ __align__(16) u16 As[BM * BK];
    __shared__ __align__(16) u16 Bs[BN * BK];

    int tid = threadIdx.x;
    int bx = blockIdx.x % (N / BN);  // 32 tiles along N
    int by = blockIdx.x / (N / BN);  // 64 tiles along M
    int m0 = by * BM, n0 = bx * BN;
    int wave = tid >> 6, lane = tid & 63;
    int wm = (wave >> 1) * 64, wn = (wave & 1) * 64;
    int lrow = lane & 15, lq = lane >> 4;

    f32x4 acc[4][4] = {};

    // staging chunk c covers tile elements [c*8, c*8+8): row=c>>2, col=(c&3)*8
    int c0 = tid, c1 = tid + 256;
    const u16* gA0 = A + (size_t)(m0 + (c0 >> 2)) * K + ((c0 & 3) << 3);
    const u16* gA1 = A + (size_t)(m0 + (c1 >> 2)) * K + ((c1 & 3) << 3);
    const u16* gB0 = Bm + (size_t)(n0 + (c0 >> 2)) * K + ((c0 & 3) << 3);
    const u16* gB1 = Bm + (size_t)(n0 + (c1 >> 2)) * K + ((c1 & 3) << 3);

    for (int k0 = 0; k0 < K; k0 += BK) {
        __builtin_amdgcn_global_load_lds(GLOBAL_AS(gA0 + k0), LDS_AS((char*)As + c0 * 16), 16, 0, 0);
        __builtin_amdgcn_global_load_lds(GLOBAL_AS(gA1 + k0), LDS_AS((char*)As + c1 * 16), 16, 0, 0);
        __builtin_amdgcn_global_load_lds(GLOBAL_AS(gB0 + k0), LDS_AS((char*)Bs + c0 * 16), 16, 0, 0);
        __builtin_amdgcn_global_load_lds(GLOBAL_AS(gB1 + k0), LDS_AS((char*)Bs + c1 * 16), 16, 0, 0);
        __builtin_amdgcn_s_waitcnt(0x0f70);  // vmcnt(0)
        __syncthreads();

        bf16x8 af[4], bfr[4];
#pragma unroll
        for (int i = 0; i < 4; ++i)
            af[i] = *(const bf16x8*)&As[(wm + i * 16 + lrow) * BK + lq * 8];
#pragma unroll
        for (int i = 0; i < 4; ++i)
            bfr[i] = *(const bf16x8*)&Bs[(wn + i * 16 + lrow) * BK + lq * 8];
#pragma unroll
        for (int i = 0; i < 4; ++i)
#pragma unroll
            for (int j = 0; j < 4; ++j)
                acc[i][j] = __builtin_amdgcn_mfma_f32_16x16x32_bf16(af[i], bfr[j], acc[i][j], 0, 0, 0);
        __syncthreads();
    }

    // epilogue: D layout col=lane&15, row=(lane>>4)*4+e
#pragma unroll
    for (int i = 0; i < 4; ++i)
#pragma unroll
        for (int j = 0; j < 4; ++j)
#pragma unroll
            for (int e = 0; e < 4; ++e) {
                int row = m0 + wm + i * 16 + lq * 4 + e;
                int col = n0 + wn + j * 16 + lrow;
                C[(size_t)row * N + col] = acc[i][j][e];
            }
}

// ---------------------------------------------------------------------------
extern "C" void kernel_launch(void* const* d_in, const int* in_sizes, int n_in,
                              void* d_out, int out_size, void* d_ws, size_t ws_size,
                              hipStream_t stream) {
    const float* x = (const float*)d_in[0];
    const float* G = (const float*)d_in[1];
    const float* H = (const float*)d_in[2];
    float* y = (float*)d_out;

    char* ws = (char*)d_ws;
    u16* xbf = (u16*)ws;                                   // 64 MB
    u16* Wbf = (u16*)(ws + (size_t)BB * NN * 2);           // 32 MB
    float* S = (float*)(ws + (size_t)BB * NN * 2 + (size_t)NN * NN * 2);  // 1 MB

    hipLaunchKernelGGL(cast_x_kernel, dim3((BB * NN / 8) / 256), dim3(256), 0, stream, x, (uint4*)xbf);
    hipLaunchKernelGGL(ksum_kernel, dim3((NN / 256) * NCHUNK), dim3(256), 0, stream, G, H, S);
    hipLaunchKernelGGL(kprefix_kernel, dim3((NN / 256) * NCHUNK), dim3(256), 0, stream, G, H, S, Wbf);
    hipLaunchKernelGGL(gemm_bt_kernel, dim3((BB / BM) * (NN / BN)), dim3(256), 0, stream, xbf, Wbf, y);
}